// Round 5
// baseline (320.226 us; speedup 1.0000x reference)
//
#include <hip/hip_runtime.h>
#include <cstdint>

// ---------------------------------------------------------------------------
// AnaphoricityScorer: scores = rough + FFNN([a, b, a*b, pw] @ W1 -> leaky -> W_out)
// Factorized: h = Ha[batch] + Hb[idx] + (a*b|pw)@W1cd + b1
// R5: 256x256 phase-split GEMM (8 waves, BK=64, 128KiB dbuf LDS):
//  - per K-tile 4 phases {ds_read | stage half -> s_barrier -> lgkmcnt(0) ->
//    setprio(1) 16xMFMA setprio(0) -> s_barrier}, raw barriers (no vmcnt drain)
//  - one vmcnt(0) per K-tile at phase 3; A staged phases 0-1 (long latency),
//    B phases 2 (L2-resident) -> max issue-to-wait distance
//  - T2 XOR swizzle (chunk ^= row&7): linear LDS dest + inverse-swizzled
//    global source (gload_lds rule) + swizzled ds_read -> kills 16-way conflict
// ---------------------------------------------------------------------------

typedef short short8 __attribute__((ext_vector_type(8)));
typedef float f32x4 __attribute__((ext_vector_type(4)));

static __device__ __forceinline__ unsigned short f2bf(float x) {
  union { float f; unsigned u; } v; v.f = x;
  unsigned r = v.u + 0x7fffu + ((v.u >> 16) & 1u);  // RNE
  return (unsigned short)(r >> 16);
}
static __device__ __forceinline__ float bf2f(unsigned short u) {
  union { unsigned u; float f; } v; v.u = ((unsigned)u) << 16;
  return v.f;
}

static __device__ __forceinline__ void gload_lds16(const void* g, void* lds) {
  __builtin_amdgcn_global_load_lds(
      (const __attribute__((address_space(1))) void*)(unsigned long long)(uintptr_t)g,
      (__attribute__((address_space(3))) void*)(unsigned)(uintptr_t)lds, 16, 0, 0);
}

// W1 [3136][1024] f32 -> W1T [1024][3136] bf16 (tiled transpose)
__global__ void k_w1t(const float* __restrict__ W1, unsigned short* __restrict__ W1T) {
  __shared__ float t[64][65];
  int k0 = blockIdx.x * 64, n0 = blockIdx.y * 64;
  int c = threadIdx.x & 63, r4 = threadIdx.x >> 6;
#pragma unroll
  for (int rr = 0; rr < 16; ++rr) {
    int r = rr * 4 + r4;
    t[r][c] = W1[(size_t)(k0 + r) * 1024 + n0 + c];
  }
  __syncthreads();
#pragma unroll
  for (int rr = 0; rr < 16; ++rr) {
    int r = rr * 4 + r4;
    W1T[(size_t)(n0 + r) * 3136 + k0 + c] = f2bf(t[c][r]);
  }
}

__global__ void k_cvt(const float* __restrict__ s, unsigned short* __restrict__ d, int n4) {
  int i = blockIdx.x * 256 + threadIdx.x;
  if (i < n4) {
    float4 v = ((const float4*)s)[i];
    ushort4 o; o.x = f2bf(v.x); o.y = f2bf(v.y); o.z = f2bf(v.z); o.w = f2bf(v.w);
    ((ushort4*)d)[i] = o;
  }
}

// P[p] = [ bf16(a)*bf16(b) (1024) | bf16(pw) (64) ]
__global__ void k_pairs(const unsigned short* __restrict__ Abm,
                        const unsigned short* __restrict__ Aball,
                        const float* __restrict__ pw, const int* __restrict__ idx,
                        unsigned short* __restrict__ P) {
  int p = blockIdx.x, tid = threadIdx.x;
  int b = p / 50;
  int g = idx[p];
  ushort4 av = ((const ushort4*)(Abm + (size_t)b * 1024))[tid];
  ushort4 bv = ((const ushort4*)(Aball + (size_t)g * 1024))[tid];
  ushort4 o;
  o.x = f2bf(bf2f(av.x) * bf2f(bv.x));
  o.y = f2bf(bf2f(av.y) * bf2f(bv.y));
  o.z = f2bf(bf2f(av.z) * bf2f(bv.z));
  o.w = f2bf(bf2f(av.w) * bf2f(bv.w));
  ((ushort4*)(P + (size_t)p * 1088))[tid] = o;
  if (tid < 16) {
    float4 pv = ((const float4*)(pw + (size_t)p * 64))[tid];
    ushort4 q; q.x = f2bf(pv.x); q.y = f2bf(pv.y); q.z = f2bf(pv.z); q.w = f2bf(pv.w);
    ((ushort4*)(P + (size_t)p * 1088 + 1024))[tid] = q;
  }
}

// Small GEMM for Ha (1024x1024), 2-phase 128x128 (grid too small for 256^2).
__global__ __launch_bounds__(256) void k_gemm0(
    const unsigned short* __restrict__ A, int ldaE, int K,
    const unsigned short* __restrict__ W1T, int koff, float* __restrict__ C) {
  __shared__ unsigned short As[2][128 * 64];
  __shared__ unsigned short Bs[2][128 * 64];
  int tid = threadIdx.x, lane = tid & 63, wave = tid >> 6;
  int row0 = blockIdx.x * 128, n0 = blockIdx.y * 128;
  int wr = wave >> 1, wc = wave & 1;
  int llo = lane & 15, lhi = lane >> 4;
  f32x4 acc[4][4] = {};
  const char* Ab = (const char*)A;
  const char* Bb = (const char*)W1T + (size_t)koff * 2;
  size_t ldaB = (size_t)ldaE * 2;
  int nkt = K >> 6;
  int o = wave * 1024 + lane * 16;
  auto stage = [&](int buf, int kt) {
#pragma unroll
    for (int c = 0; c < 4; ++c) {
      int oo = c * 4096 + o;
      int rr = oo >> 7, kb = oo & 127;
      gload_lds16(Ab + (size_t)(row0 + rr) * ldaB + (size_t)kt * 128 + kb,
                  (char*)As + buf * 16384 + oo);
      gload_lds16(Bb + (size_t)(n0 + rr) * 6272 + (size_t)kt * 128 + kb,
                  (char*)Bs + buf * 16384 + oo);
    }
  };
  stage(0, 0);
  __syncthreads();
  int cur = 0;
  for (int kt = 0; kt < nkt; ++kt) {
    if (kt + 1 < nkt) stage(cur ^ 1, kt + 1);
    const unsigned short* as = As[cur];
    const unsigned short* bs = Bs[cur];
#pragma unroll
    for (int ks = 0; ks < 2; ++ks) {
      short8 af[4], bfr[4];
#pragma unroll
      for (int m = 0; m < 4; ++m)
        af[m] = *(const short8*)(as + (wr * 64 + m * 16 + llo) * 64 + ks * 32 + lhi * 8);
#pragma unroll
      for (int n = 0; n < 4; ++n)
        bfr[n] = *(const short8*)(bs + (wc * 64 + n * 16 + llo) * 64 + ks * 32 + lhi * 8);
#pragma unroll
      for (int m = 0; m < 4; ++m)
#pragma unroll
        for (int n = 0; n < 4; ++n)
          acc[m][n] = __builtin_amdgcn_mfma_f32_16x16x32_bf16(af[m], bfr[n], acc[m][n], 0, 0, 0);
    }
    __syncthreads();
    cur ^= 1;
  }
#pragma unroll
  for (int m = 0; m < 4; ++m)
#pragma unroll
    for (int i = 0; i < 4; ++i) {
      int tr = wr * 64 + m * 16 + lhi * 4 + i;
#pragma unroll
      for (int n = 0; n < 4; ++n)
        C[(size_t)(row0 + tr) * 1024 + n0 + wc * 64 + n * 16 + llo] = acc[m][n][i];
    }
}

// 256x256 phase-split GEMM. EPI=0: C[M][1024]. EPI=1: fused scorer epilogue.
// Grid must be multiple of 8; N fixed at 1024 (4 n-tiles, y fastest in swizzle).
template <int EPI>
__global__ __launch_bounds__(512) void k_g8(
    const unsigned short* __restrict__ A, int ldaE, int nkt,
    const unsigned short* __restrict__ W1T, int koff,
    float* __restrict__ C, float* __restrict__ partial,
    const float* __restrict__ Ha, const float* __restrict__ Hb,
    const float* __restrict__ b1, const float* __restrict__ Wout,
    const int* __restrict__ idx) {
  __shared__ unsigned short As[2][16384];  // 2 x 256rows x 64k bf16 (32KB/slot)
  __shared__ unsigned short Bs[2][16384];
  int tid = threadIdx.x, lane = tid & 63, wave = tid >> 6;
  int wm = wave >> 2, wn = wave & 3;      // 2M x 4N wave grid, 128x64 per wave
  int llo = lane & 15, lhi = lane >> 4;
  int cpx = gridDim.x >> 3;               // XCD-chunked bijective swizzle
  int orig = (blockIdx.x & 7) * cpx + (blockIdx.x >> 3);
  int x = orig >> 2, y = orig & 3;        // y (n-tile) fastest within chunk
  int row0 = x * 256, n0 = y * 256;
  const char* Ab = (const char*)A;
  const char* Bb = (const char*)W1T + (size_t)koff * 2;
  size_t ldaB = (size_t)ldaE * 2;
  // staging constants: thread writes LDS bytes [tid*16+r*8192+h*16384, +16)
  // (linear dest). Source chunk inverse-swizzled: j = (tid&7) ^ (row&7).
  int grow = tid >> 3;
  int j16 = (((tid & 7) ^ (grow & 7)) << 4);
  f32x4 acc[8][4] = {};

  auto stageA = [&](int b, int kt, int h) {
#pragma unroll
    for (int r2 = 0; r2 < 2; ++r2) {
      int o = h * 16384 + r2 * 8192 + tid * 16;
      gload_lds16(Ab + (size_t)(row0 + h * 128 + r2 * 64 + grow) * ldaB +
                      (size_t)kt * 128 + j16,
                  (char*)(&As[b][0]) + o);
    }
  };
  auto stageB = [&](int b, int kt, int h) {
#pragma unroll
    for (int r2 = 0; r2 < 2; ++r2) {
      int o = h * 16384 + r2 * 8192 + tid * 16;
      gload_lds16(Bb + (size_t)(n0 + h * 128 + r2 * 64 + grow) * 6272 +
                      (size_t)kt * 128 + j16,
                  (char*)(&Bs[b][0]) + o);
    }
  };

  // prologue: stage K-tile 0 into buf 0
  stageA(0, 0, 0); stageA(0, 0, 1); stageB(0, 0, 0); stageB(0, 0, 1);
  asm volatile("s_waitcnt vmcnt(0)" ::: "memory");
  __builtin_amdgcn_s_barrier();
  __builtin_amdgcn_sched_barrier(0);

  for (int kt = 0; kt < nkt; ++kt) {
    int cur = kt & 1;
    const char* as = (const char*)(&As[cur][0]);
    const char* bs = (const char*)(&Bs[cur][0]);
    bool pre = (kt + 1 < nkt);
    short8 bfr[4][2];
#pragma unroll
    for (int q = 0; q < 4; ++q) {
      // ds_read fragments (swizzled chunk: j = (ks*4+lhi) ^ (llo&7))
      short8 af[2][2];
#pragma unroll
      for (int mm = 0; mm < 2; ++mm)
#pragma unroll
        for (int ks = 0; ks < 2; ++ks) {
          int row = wm * 128 + (2 * q + mm) * 16 + llo;
          int j = ((ks << 2) | lhi) ^ (llo & 7);
          af[mm][ks] = *(const short8*)(as + row * 128 + j * 16);
        }
      if (q == 0) {
#pragma unroll
        for (int n = 0; n < 4; ++n)
#pragma unroll
          for (int ks = 0; ks < 2; ++ks) {
            int row = wn * 64 + n * 16 + llo;
            int j = ((ks << 2) | lhi) ^ (llo & 7);
            bfr[n][ks] = *(const short8*)(bs + row * 128 + j * 16);
          }
      }
      // stage next K-tile: A (long latency) first, B (L2) later
      if (pre) {
        if (q == 0) stageA(cur ^ 1, kt + 1, 0);
        else if (q == 1) stageA(cur ^ 1, kt + 1, 1);
        else if (q == 2) { stageB(cur ^ 1, kt + 1, 0); stageB(cur ^ 1, kt + 1, 1); }
      }
      if (q == 3) asm volatile("s_waitcnt vmcnt(0)" ::: "memory");
      __builtin_amdgcn_s_barrier();
      asm volatile("s_waitcnt lgkmcnt(0)" ::: "memory");
      __builtin_amdgcn_sched_barrier(0);
      __builtin_amdgcn_s_setprio(1);
#pragma unroll
      for (int mm = 0; mm < 2; ++mm)
#pragma unroll
        for (int n = 0; n < 4; ++n)
#pragma unroll
          for (int ks = 0; ks < 2; ++ks)
            acc[2 * q + mm][n] = __builtin_amdgcn_mfma_f32_16x16x32_bf16(
                af[mm][ks], bfr[n][ks], acc[2 * q + mm][n], 0, 0, 0);
      __builtin_amdgcn_s_setprio(0);
      __builtin_amdgcn_sched_barrier(0);
      __builtin_amdgcn_s_barrier();
      __builtin_amdgcn_sched_barrier(0);
    }
  }

  if (EPI == 0) {
#pragma unroll
    for (int m = 0; m < 8; ++m)
#pragma unroll
      for (int i = 0; i < 4; ++i) {
        int tr = wm * 128 + m * 16 + lhi * 4 + i;
#pragma unroll
        for (int n = 0; n < 4; ++n)
          C[(size_t)(row0 + tr) * 1024 + n0 + wn * 64 + n * 16 + llo] = acc[m][n][i];
      }
  } else {
    float b1v[4], wov[4];
    int coln[4];
#pragma unroll
    for (int n = 0; n < 4; ++n) {
      coln[n] = n0 + wn * 64 + n * 16 + llo;
      b1v[n] = b1[coln[n]];
      wov[n] = Wout[coln[n]];
    }
    int chunk = (n0 >> 6) + wn;
#pragma unroll
    for (int m = 0; m < 8; ++m)
#pragma unroll
      for (int i = 0; i < 4; ++i) {
        int p = row0 + wm * 128 + m * 16 + lhi * 4 + i;
        int bb = p / 50;
        int gg = idx[p];
        const float* Har = Ha + (size_t)bb * 1024;
        const float* Hbr = Hb + (size_t)gg * 1024;
        float s = 0.f;
#pragma unroll
        for (int n = 0; n < 4; ++n) {
          float h = acc[m][n][i] + Har[coln[n]] + Hbr[coln[n]] + b1v[n];
          h = h > 0.f ? h : 0.01f * h;
          s += h * wov[n];
        }
        s += __shfl_xor(s, 1, 64);
        s += __shfl_xor(s, 2, 64);
        s += __shfl_xor(s, 4, 64);
        s += __shfl_xor(s, 8, 64);
        if (llo == 0) partial[(size_t)p * 16 + chunk] = s;
      }
  }
}

__global__ void k_final(const float* __restrict__ partial, const float* __restrict__ rough,
                        const float* __restrict__ bout, float* __restrict__ out) {
  int t = blockIdx.x * 256 + threadIdx.x;
  if (t < 51200) {
    float s = rough[t] + bout[0];
    const float* pp = partial + (size_t)t * 16;
#pragma unroll
    for (int c = 0; c < 16; ++c) s += pp[c];
    out[(size_t)(t / 50) * 51 + 1 + (t % 50)] = s;
  }
  if (t < 1024) out[(size_t)t * 51] = 1e-7f;
}

extern "C" void kernel_launch(void* const* d_in, const int* in_sizes, int n_in,
                              void* d_out, int out_size, void* d_ws, size_t ws_size,
                              hipStream_t stream) {
  (void)in_sizes; (void)n_in; (void)out_size;
  const float* allm  = (const float*)d_in[0];  // [8192][1024]
  const float* am    = (const float*)d_in[1];  // [1024][1024]
  const float* pw    = (const float*)d_in[2];  // [1024][50][64]
  const float* rough = (const float*)d_in[3];  // [1024][50]
  const float* W1    = (const float*)d_in[4];  // [3136][1024]
  const float* b1    = (const float*)d_in[5];  // [1024]
  const float* Wout  = (const float*)d_in[6];  // [1024]
  const float* bout  = (const float*)d_in[7];  // [1]
  const int*   idx   = (const int*)d_in[8];    // [1024][50]
  float* out = (float*)d_out;                  // [1024][51]

  char* w = (char*)d_ws;
  unsigned short* W1T   = (unsigned short*)w; w += (size_t)1024 * 3136 * 2;
  unsigned short* Abm   = (unsigned short*)w; w += (size_t)1024 * 1024 * 2;
  unsigned short* Aball = (unsigned short*)w; w += (size_t)8192 * 1024 * 2;
  unsigned short* P     = (unsigned short*)w; w += (size_t)51200 * 1088 * 2;
  float* Ha             = (float*)w;          w += (size_t)1024 * 1024 * 4;
  float* Hb             = (float*)w;          w += (size_t)8192 * 1024 * 4;
  float* part           = (float*)w;          w += (size_t)51200 * 16 * 4;
  size_t need = (size_t)(w - (char*)d_ws);
  if (ws_size < need) return;

  k_w1t<<<dim3(49, 16), 256, 0, stream>>>(W1, W1T);
  k_cvt<<<dim3(1024), 256, 0, stream>>>(am, Abm, 1024 * 1024 / 4);
  k_cvt<<<dim3(8192), 256, 0, stream>>>(allm, Aball, 8192 * 1024 / 4);
  k_pairs<<<dim3(51200), 256, 0, stream>>>(Abm, Aball, pw, idx, P);
  k_gemm0<<<dim3(8, 8), 256, 0, stream>>>(Abm, 1024, 1024, W1T, 0, Ha);
  k_g8<0><<<dim3(128), 512, 0, stream>>>(Aball, 1024, 16, W1T, 1024, Hb, nullptr,
                                         nullptr, nullptr, nullptr, nullptr, nullptr);
  k_g8<1><<<dim3(800), 512, 0, stream>>>(P, 1088, 17, W1T, 2048, nullptr, part,
                                         Ha, Hb, b1, Wout, idx);
  k_final<<<dim3(200), 256, 0, stream>>>(part, rough, bout, out);
}

// Round 6
// 292.821 us; speedup vs baseline: 1.0936x; 1.0936x over previous
//
#include <hip/hip_runtime.h>
#include <cstdint>

// ---------------------------------------------------------------------------
// AnaphoricityScorer: scores = rough + FFNN([a, b, a*b, pw] @ W1 -> leaky -> W_out)
// Factorized: h = Ha[batch] + Hb[idx] + (a*b|pw)@W1cd + b1
// R6: counted-vmcnt pipeline (T4) — per K-tile:
//   s_barrier -> stage(t+1) [8 loads] -> vmcnt(8) [waits loads issued 1 tile
//   ago] -> s_barrier -> unbarriered ds_read+64xMFMA body.
//   2 barriers/tile, ZERO vmcnt(0) drains in steady state (vs R5's 8 barriers
//   + 1 drain). T2 XOR swizzle kept (verified: conflicts 4.2e7 -> 0).
//   Hb moved back to 128^2 k_gemm0 (512 blocks, 2/CU) with same upgrades.
// ---------------------------------------------------------------------------

typedef short short8 __attribute__((ext_vector_type(8)));
typedef float f32x4 __attribute__((ext_vector_type(4)));

static __device__ __forceinline__ unsigned short f2bf(float x) {
  union { float f; unsigned u; } v; v.f = x;
  unsigned r = v.u + 0x7fffu + ((v.u >> 16) & 1u);  // RNE
  return (unsigned short)(r >> 16);
}
static __device__ __forceinline__ float bf2f(unsigned short u) {
  union { unsigned u; float f; } v; v.u = ((unsigned)u) << 16;
  return v.f;
}

static __device__ __forceinline__ void gload_lds16(const void* g, void* lds) {
  __builtin_amdgcn_global_load_lds(
      (const __attribute__((address_space(1))) void*)(unsigned long long)(uintptr_t)g,
      (__attribute__((address_space(3))) void*)(unsigned)(uintptr_t)lds, 16, 0, 0);
}

// W1 [3136][1024] f32 -> W1T [1024][3136] bf16 (tiled transpose)
__global__ void k_w1t(const float* __restrict__ W1, unsigned short* __restrict__ W1T) {
  __shared__ float t[64][65];
  int k0 = blockIdx.x * 64, n0 = blockIdx.y * 64;
  int c = threadIdx.x & 63, r4 = threadIdx.x >> 6;
#pragma unroll
  for (int rr = 0; rr < 16; ++rr) {
    int r = rr * 4 + r4;
    t[r][c] = W1[(size_t)(k0 + r) * 1024 + n0 + c];
  }
  __syncthreads();
#pragma unroll
  for (int rr = 0; rr < 16; ++rr) {
    int r = rr * 4 + r4;
    W1T[(size_t)(n0 + r) * 3136 + k0 + c] = f2bf(t[c][r]);
  }
}

__global__ void k_cvt(const float* __restrict__ s, unsigned short* __restrict__ d, int n4) {
  int i = blockIdx.x * 256 + threadIdx.x;
  if (i < n4) {
    float4 v = ((const float4*)s)[i];
    ushort4 o; o.x = f2bf(v.x); o.y = f2bf(v.y); o.z = f2bf(v.z); o.w = f2bf(v.w);
    ((ushort4*)d)[i] = o;
  }
}

// P[p] = [ bf16(a)*bf16(b) (1024) | bf16(pw) (64) ]
__global__ void k_pairs(const unsigned short* __restrict__ Abm,
                        const unsigned short* __restrict__ Aball,
                        const float* __restrict__ pw, const int* __restrict__ idx,
                        unsigned short* __restrict__ P) {
  int p = blockIdx.x, tid = threadIdx.x;
  int b = p / 50;
  int g = idx[p];
  ushort4 av = ((const ushort4*)(Abm + (size_t)b * 1024))[tid];
  ushort4 bv = ((const ushort4*)(Aball + (size_t)g * 1024))[tid];
  ushort4 o;
  o.x = f2bf(bf2f(av.x) * bf2f(bv.x));
  o.y = f2bf(bf2f(av.y) * bf2f(bv.y));
  o.z = f2bf(bf2f(av.z) * bf2f(bv.z));
  o.w = f2bf(bf2f(av.w) * bf2f(bv.w));
  ((ushort4*)(P + (size_t)p * 1088))[tid] = o;
  if (tid < 16) {
    float4 pv = ((const float4*)(pw + (size_t)p * 64))[tid];
    ushort4 q; q.x = f2bf(pv.x); q.y = f2bf(pv.y); q.z = f2bf(pv.z); q.w = f2bf(pv.w);
    ((ushort4*)(P + (size_t)p * 1088 + 1024))[tid] = q;
  }
}

// 128x128 GEMM (Ha, Hb): counted-vmcnt pipeline + XOR swizzle.
__global__ __launch_bounds__(256) void k_gemm0(
    const unsigned short* __restrict__ A, int ldaE, int K,
    const unsigned short* __restrict__ W1T, int koff, float* __restrict__ C) {
  __shared__ unsigned short As[2][8192];
  __shared__ unsigned short Bs[2][8192];
  int tid = threadIdx.x, lane = tid & 63, wave = tid >> 6;
  int row0 = blockIdx.x * 128, n0 = blockIdx.y * 128;
  int wr = wave >> 1, wc = wave & 1;
  int llo = lane & 15, lhi = lane >> 4;
  f32x4 acc[4][4] = {};
  const char* Ab = (const char*)A;
  const char* Bb = (const char*)W1T + (size_t)koff * 2;
  size_t ldaB = (size_t)ldaE * 2;
  int nkt = K >> 6;
  int grow = tid >> 3;  // 0..31
  int j16 = (((tid & 7) ^ (grow & 7)) << 4);

  auto stage = [&](int b, int kt) {
#pragma unroll
    for (int r2 = 0; r2 < 4; ++r2) {
      gload_lds16(Ab + (size_t)(row0 + r2 * 32 + grow) * ldaB + (size_t)kt * 128 + j16,
                  (char*)(&As[b][0]) + r2 * 4096 + tid * 16);
      gload_lds16(Bb + (size_t)(n0 + r2 * 32 + grow) * 6272 + (size_t)kt * 128 + j16,
                  (char*)(&Bs[b][0]) + r2 * 4096 + tid * 16);
    }
  };

  stage(0, 0);
  for (int kt = 0; kt < nkt; ++kt) {
    int cur = kt & 1;
    __builtin_amdgcn_s_barrier();
    __builtin_amdgcn_sched_barrier(0);
    if (kt + 1 < nkt) {
      stage(cur ^ 1, kt + 1);
      asm volatile("s_waitcnt vmcnt(8)" ::: "memory");
    } else {
      asm volatile("s_waitcnt vmcnt(0)" ::: "memory");
    }
    __builtin_amdgcn_s_barrier();
    __builtin_amdgcn_sched_barrier(0);
    const char* as = (const char*)(&As[cur][0]);
    const char* bs = (const char*)(&Bs[cur][0]);
    short8 bfr[4][2];
#pragma unroll
    for (int n = 0; n < 4; ++n)
#pragma unroll
      for (int ks = 0; ks < 2; ++ks) {
        int row = wc * 64 + n * 16 + llo;
        int j = ((ks << 2) | lhi) ^ (llo & 7);
        bfr[n][ks] = *(const short8*)(bs + row * 128 + j * 16);
      }
#pragma unroll
    for (int m = 0; m < 4; ++m) {
      short8 af[2];
#pragma unroll
      for (int ks = 0; ks < 2; ++ks) {
        int row = wr * 64 + m * 16 + llo;
        int j = ((ks << 2) | lhi) ^ (llo & 7);
        af[ks] = *(const short8*)(as + row * 128 + j * 16);
      }
#pragma unroll
      for (int n = 0; n < 4; ++n)
#pragma unroll
        for (int ks = 0; ks < 2; ++ks)
          acc[m][n] = __builtin_amdgcn_mfma_f32_16x16x32_bf16(af[ks], bfr[n][ks], acc[m][n], 0, 0, 0);
    }
  }
#pragma unroll
  for (int m = 0; m < 4; ++m)
#pragma unroll
    for (int i = 0; i < 4; ++i) {
      int tr = wr * 64 + m * 16 + lhi * 4 + i;
#pragma unroll
      for (int n = 0; n < 4; ++n)
        C[(size_t)(row0 + tr) * 1024 + n0 + wc * 64 + n * 16 + llo] = acc[m][n][i];
    }
}

// Main 256x256 GEMM, counted-vmcnt pipeline, fused scorer epilogue.
// Grid 800 = 200 row-tiles x 4 n-tiles, XCD-chunked bijective swizzle.
__global__ __launch_bounds__(512) void k_main256(
    const unsigned short* __restrict__ P, const unsigned short* __restrict__ W1T,
    float* __restrict__ partial,
    const float* __restrict__ Ha, const float* __restrict__ Hb,
    const float* __restrict__ b1, const float* __restrict__ Wout,
    const int* __restrict__ idx) {
  __shared__ unsigned short As[2][16384];
  __shared__ unsigned short Bs[2][16384];
  int tid = threadIdx.x, lane = tid & 63, wave = tid >> 6;
  int wm = wave >> 2, wn = wave & 3;  // 2M x 4N waves, each owns 128x64 of C
  int llo = lane & 15, lhi = lane >> 4;
  int cpx = gridDim.x >> 3;
  int orig = (blockIdx.x & 7) * cpx + (blockIdx.x >> 3);
  int x = orig >> 2, y = orig & 3;    // y (n-tile) fastest within XCD chunk
  int row0 = x * 256, n0 = y * 256;
  const char* Ab = (const char*)P;
  const char* Bb = (const char*)W1T + 2048 * 2;  // koff = 2048
  const size_t ldaB = 2176;
  int grow = tid >> 3;  // 0..63
  int j16 = (((tid & 7) ^ (grow & 7)) << 4);
  f32x4 acc[8][4] = {};

  auto stage = [&](int b, int kt) {
#pragma unroll
    for (int r2 = 0; r2 < 4; ++r2)
      gload_lds16(Ab + (size_t)(row0 + r2 * 64 + grow) * ldaB + (size_t)kt * 128 + j16,
                  (char*)(&As[b][0]) + r2 * 8192 + tid * 16);
#pragma unroll
    for (int r2 = 0; r2 < 4; ++r2)
      gload_lds16(Bb + (size_t)(n0 + r2 * 64 + grow) * 6272 + (size_t)kt * 128 + j16,
                  (char*)(&Bs[b][0]) + r2 * 8192 + tid * 16);
  };

  stage(0, 0);
  const int nkt = 17;
  for (int kt = 0; kt < nkt; ++kt) {
    int cur = kt & 1;
    __builtin_amdgcn_s_barrier();          // all waves done reading buf cur^1
    __builtin_amdgcn_sched_barrier(0);
    if (kt + 1 < nkt) {
      stage(cur ^ 1, kt + 1);              // 8 loads into buf cur^1
      asm volatile("s_waitcnt vmcnt(8)" ::: "memory");  // tile-t loads done
    } else {
      asm volatile("s_waitcnt vmcnt(0)" ::: "memory");
    }
    __builtin_amdgcn_s_barrier();          // block-wide: tile-t LDS ready
    __builtin_amdgcn_sched_barrier(0);
    const char* as = (const char*)(&As[cur][0]);
    const char* bs = (const char*)(&Bs[cur][0]);
    short8 bfr[4][2];
#pragma unroll
    for (int n = 0; n < 4; ++n)
#pragma unroll
      for (int ks = 0; ks < 2; ++ks) {
        int row = wn * 64 + n * 16 + llo;
        int j = ((ks << 2) | lhi) ^ (llo & 7);
        bfr[n][ks] = *(const short8*)(bs + row * 128 + j * 16);
      }
#pragma unroll
    for (int m = 0; m < 8; ++m) {
      short8 af[2];
#pragma unroll
      for (int ks = 0; ks < 2; ++ks) {
        int row = wm * 128 + m * 16 + llo;
        int j = ((ks << 2) | lhi) ^ (llo & 7);
        af[ks] = *(const short8*)(as + row * 128 + j * 16);
      }
#pragma unroll
      for (int n = 0; n < 4; ++n)
#pragma unroll
        for (int ks = 0; ks < 2; ++ks)
          acc[m][n] = __builtin_amdgcn_mfma_f32_16x16x32_bf16(af[ks], bfr[n][ks], acc[m][n], 0, 0, 0);
    }
  }

  // fused epilogue -> partial[p][16]
  float b1v[4], wov[4];
  int coln[4];
#pragma unroll
  for (int n = 0; n < 4; ++n) {
    coln[n] = n0 + wn * 64 + n * 16 + llo;
    b1v[n] = b1[coln[n]];
    wov[n] = Wout[coln[n]];
  }
  int chunk = y * 4 + wn;
#pragma unroll
  for (int m = 0; m < 8; ++m)
#pragma unroll
    for (int i = 0; i < 4; ++i) {
      int p = row0 + wm * 128 + m * 16 + lhi * 4 + i;
      int bb = p / 50;
      int gg = idx[p];
      const float* Har = Ha + (size_t)bb * 1024;
      const float* Hbr = Hb + (size_t)gg * 1024;
      float s = 0.f;
#pragma unroll
      for (int n = 0; n < 4; ++n) {
        float h = acc[m][n][i] + Har[coln[n]] + Hbr[coln[n]] + b1v[n];
        h = h > 0.f ? h : 0.01f * h;
        s += h * wov[n];
      }
      s += __shfl_xor(s, 1, 64);
      s += __shfl_xor(s, 2, 64);
      s += __shfl_xor(s, 4, 64);
      s += __shfl_xor(s, 8, 64);
      if (llo == 0) partial[(size_t)p * 16 + chunk] = s;
    }
}

__global__ void k_final(const float* __restrict__ partial, const float* __restrict__ rough,
                        const float* __restrict__ bout, float* __restrict__ out) {
  int t = blockIdx.x * 256 + threadIdx.x;
  if (t < 51200) {
    float s = rough[t] + bout[0];
    const float* pp = partial + (size_t)t * 16;
#pragma unroll
    for (int c = 0; c < 16; ++c) s += pp[c];
    out[(size_t)(t / 50) * 51 + 1 + (t % 50)] = s;
  }
  if (t < 1024) out[(size_t)t * 51] = 1e-7f;
}

extern "C" void kernel_launch(void* const* d_in, const int* in_sizes, int n_in,
                              void* d_out, int out_size, void* d_ws, size_t ws_size,
                              hipStream_t stream) {
  (void)in_sizes; (void)n_in; (void)out_size;
  const float* allm  = (const float*)d_in[0];  // [8192][1024]
  const float* am    = (const float*)d_in[1];  // [1024][1024]
  const float* pw    = (const float*)d_in[2];  // [1024][50][64]
  const float* rough = (const float*)d_in[3];  // [1024][50]
  const float* W1    = (const float*)d_in[4];  // [3136][1024]
  const float* b1    = (const float*)d_in[5];  // [1024]
  const float* Wout  = (const float*)d_in[6];  // [1024]
  const float* bout  = (const float*)d_in[7];  // [1]
  const int*   idx   = (const int*)d_in[8];    // [1024][50]
  float* out = (float*)d_out;                  // [1024][51]

  char* w = (char*)d_ws;
  unsigned short* W1T   = (unsigned short*)w; w += (size_t)1024 * 3136 * 2;
  unsigned short* Abm   = (unsigned short*)w; w += (size_t)1024 * 1024 * 2;
  unsigned short* Aball = (unsigned short*)w; w += (size_t)8192 * 1024 * 2;
  unsigned short* P     = (unsigned short*)w; w += (size_t)51200 * 1088 * 2;
  float* Ha             = (float*)w;          w += (size_t)1024 * 1024 * 4;
  float* Hb             = (float*)w;          w += (size_t)8192 * 1024 * 4;
  float* part           = (float*)w;          w += (size_t)51200 * 16 * 4;
  size_t need = (size_t)(w - (char*)d_ws);
  if (ws_size < need) return;

  k_w1t<<<dim3(49, 16), 256, 0, stream>>>(W1, W1T);
  k_cvt<<<dim3(1024), 256, 0, stream>>>(am, Abm, 1024 * 1024 / 4);
  k_cvt<<<dim3(8192), 256, 0, stream>>>(allm, Aball, 8192 * 1024 / 4);
  k_pairs<<<dim3(51200), 256, 0, stream>>>(Abm, Aball, pw, idx, P);
  k_gemm0<<<dim3(8, 8), 256, 0, stream>>>(Abm, 1024, 1024, W1T, 0, Ha);
  k_gemm0<<<dim3(64, 8), 256, 0, stream>>>(Aball, 1024, 1024, W1T, 1024, Hb);
  k_main256<<<dim3(800), 512, 0, stream>>>(P, W1T, part, Ha, Hb, b1, Wout, idx);
  k_final<<<dim3(200), 256, 0, stream>>>(part, rough, bout, out);
}